// Round 1
// baseline (16157.951 us; speedup 1.0000x reference)
//
#include <hip/hip_runtime.h>
#include <hip/hip_bf16.h>
#include <math.h>

// Problem constants
#define B_ 8
#define N_ 1025
#define C_ 3200
#define H_ 25
#define D_ 128
#define M_ (B_ * N_)       // 8200 rows
#define C3_ (3 * C_)       // 9600

// ---------------------------------------------------------------------------
// fp32 tiled GEMM: C[M,N] = A[M,K] @ B[K,N] + bias[N]
// 64x64 tile, BK=16, 256 threads, 4x4 micro-tile per thread.
// ---------------------------------------------------------------------------
__global__ __launch_bounds__(256) void gemm_bias_f32(
    const float* __restrict__ A, const float* __restrict__ Bm,
    const float* __restrict__ bias, float* __restrict__ C,
    int M, int N, int K)
{
    __shared__ float As[16][68];   // [kk][row-in-tile], pad 68 -> float4-aligned rows
    __shared__ float Bs[16][68];   // [kk][col-in-tile]

    const int tid = threadIdx.x;
    const int tx = tid & 15;       // 0..15 -> col group
    const int ty = tid >> 4;       // 0..15 -> row group
    const int rowBase = blockIdx.y * 64;
    const int colBase = blockIdx.x * 64;

    float acc[4][4] = {};

    for (int k0 = 0; k0 < K; k0 += 16) {
        // Load A tile (64 rows x 16 k), store transposed As[kk][i]
        #pragma unroll
        for (int l = 0; l < 4; ++l) {
            int idx = tid + l * 256;
            int i  = idx >> 4;
            int kk = idx & 15;
            int gr = rowBase + i;
            As[kk][i] = (gr < M) ? A[(size_t)gr * K + k0 + kk] : 0.f;
        }
        // Load B tile (16 k x 64 cols)
        #pragma unroll
        for (int l = 0; l < 4; ++l) {
            int idx = tid + l * 256;
            int kk = idx >> 6;
            int j  = idx & 63;
            int gc = colBase + j;
            Bs[kk][j] = (gc < N) ? Bm[(size_t)(k0 + kk) * N + gc] : 0.f;
        }
        __syncthreads();

        #pragma unroll
        for (int kk = 0; kk < 16; ++kk) {
            float4 a4 = *(const float4*)&As[kk][ty * 4];
            float4 b4 = *(const float4*)&Bs[kk][tx * 4];
            float ar[4] = {a4.x, a4.y, a4.z, a4.w};
            float br[4] = {b4.x, b4.y, b4.z, b4.w};
            #pragma unroll
            for (int i = 0; i < 4; ++i)
                #pragma unroll
                for (int j = 0; j < 4; ++j)
                    acc[i][j] += ar[i] * br[j];
        }
        __syncthreads();
    }

    #pragma unroll
    for (int i = 0; i < 4; ++i) {
        int gr = rowBase + ty * 4 + i;
        if (gr >= M) continue;
        #pragma unroll
        for (int j = 0; j < 4; ++j) {
            int gc = colBase + tx * 4 + j;
            if (gc < N) C[(size_t)gr * N + gc] = acc[i][j] + bias[gc];
        }
    }
}

// ---------------------------------------------------------------------------
// RMSNorm over full C=3200 for q (offset 0) and k (offset C) slices of qkv.
// grid = M*2 blocks, 256 threads.
// ---------------------------------------------------------------------------
__global__ __launch_bounds__(256) void rmsnorm_kernel(
    float* __restrict__ qkv, const float* __restrict__ qw,
    const float* __restrict__ kw)
{
    const int row   = blockIdx.x >> 1;
    const int which = blockIdx.x & 1;
    float* p = qkv + (size_t)row * C3_ + which * C_;
    const float* w = which ? kw : qw;
    const int tid = threadIdx.x;

    float ss = 0.f;
    for (int i = tid; i < C_; i += 256) {
        float v = p[i];
        ss += v * v;
    }
    #pragma unroll
    for (int off = 32; off; off >>= 1) ss += __shfl_down(ss, off);

    __shared__ float wsum[4];
    __shared__ float stot;
    if ((tid & 63) == 0) wsum[tid >> 6] = ss;
    __syncthreads();
    if (tid == 0) stot = wsum[0] + wsum[1] + wsum[2] + wsum[3];
    __syncthreads();

    const float scale = rsqrtf(stot / (float)C_ + 1e-6f);
    for (int i = tid; i < C_; i += 256) p[i] = p[i] * scale * w[i];
}

// ---------------------------------------------------------------------------
// Flash attention: one block handles 32 queries of one (b,h).
// K/V tiles of 32 staged in LDS; online softmax; O in registers.
// Thread (r,g): r = query row 0..31, g = 0..7 covers cols (S) / d-range (O).
// ---------------------------------------------------------------------------
#define FA_LDV 132

__global__ __launch_bounds__(256) void flash_kernel(
    const float* __restrict__ qkv, float* __restrict__ attn_out)
{
    __shared__ float Qs[32][FA_LDV];
    __shared__ float Ks[32][FA_LDV];
    __shared__ float Vs[32][FA_LDV];
    __shared__ float Ps[32][33];

    const int b  = blockIdx.z;
    const int h  = blockIdx.y;
    const int q0 = blockIdx.x * 32;
    const int tid = threadIdx.x;
    const int r = tid >> 3;   // query row in tile
    const int g = tid & 7;    // group
    const float scale = 0.088388347648318447f;  // 1/sqrt(128)

    // Load Q tile (scaled)
    #pragma unroll
    for (int l = 0; l < 16; ++l) {
        int idx = tid + l * 256;
        int i = idx >> 7, d = idx & 127;
        int q = q0 + i;
        Qs[i][d] = (q < N_) ? qkv[((size_t)(b * N_ + q)) * C3_ + h * D_ + d] * scale
                            : 0.f;
    }

    float4 o0 = {0,0,0,0}, o1 = {0,0,0,0}, o2 = {0,0,0,0}, o3 = {0,0,0,0};
    float m = -INFINITY, l_sum = 0.f;

    const int nkt = (N_ + 31) / 32;
    for (int kt = 0; kt < nkt; ++kt) {
        const int k0 = kt * 32;
        __syncthreads();   // protect Ks/Vs from previous iteration's readers
        #pragma unroll
        for (int l = 0; l < 16; ++l) {
            int idx = tid + l * 256;
            int i = idx >> 7, d = idx & 127;
            int kk = k0 + i;
            if (kk < N_) {
                size_t base = ((size_t)(b * N_ + kk)) * C3_ + h * D_ + d;
                Ks[i][d] = qkv[base + C_];
                Vs[i][d] = qkv[base + 2 * C_];
            } else {
                Ks[i][d] = 0.f;
                Vs[i][d] = 0.f;
            }
        }
        __syncthreads();

        // S = Q . K^T  (each thread: 4 cols c0..c0+3 of its row r)
        const int c0 = g * 4;
        float s0 = 0.f, s1 = 0.f, s2 = 0.f, s3 = 0.f;
        #pragma unroll 4
        for (int d = 0; d < D_; d += 4) {
            float4 qv = *(const float4*)&Qs[r][d];
            float4 ka = *(const float4*)&Ks[c0 + 0][d];
            float4 kb = *(const float4*)&Ks[c0 + 1][d];
            float4 kc = *(const float4*)&Ks[c0 + 2][d];
            float4 kd = *(const float4*)&Ks[c0 + 3][d];
            s0 += qv.x*ka.x + qv.y*ka.y + qv.z*ka.z + qv.w*ka.w;
            s1 += qv.x*kb.x + qv.y*kb.y + qv.z*kb.z + qv.w*kb.w;
            s2 += qv.x*kc.x + qv.y*kc.y + qv.z*kc.z + qv.w*kc.w;
            s3 += qv.x*kd.x + qv.y*kd.y + qv.z*kd.z + qv.w*kd.w;
        }
        if (k0 + c0 + 0 >= N_) s0 = -INFINITY;
        if (k0 + c0 + 1 >= N_) s1 = -INFINITY;
        if (k0 + c0 + 2 >= N_) s2 = -INFINITY;
        if (k0 + c0 + 3 >= N_) s3 = -INFINITY;

        // Online softmax (row-group of 8 lanes, contiguous in wave)
        float mloc = fmaxf(fmaxf(s0, s1), fmaxf(s2, s3));
        #pragma unroll
        for (int off = 1; off < 8; off <<= 1)
            mloc = fmaxf(mloc, __shfl_xor(mloc, off));
        float mnew  = fmaxf(m, mloc);
        float alpha = __expf(m - mnew);
        float p0 = __expf(s0 - mnew), p1 = __expf(s1 - mnew);
        float p2 = __expf(s2 - mnew), p3 = __expf(s3 - mnew);
        float ls = p0 + p1 + p2 + p3;
        #pragma unroll
        for (int off = 1; off < 8; off <<= 1) ls += __shfl_xor(ls, off);
        l_sum = l_sum * alpha + ls;
        m = mnew;

        o0.x *= alpha; o0.y *= alpha; o0.z *= alpha; o0.w *= alpha;
        o1.x *= alpha; o1.y *= alpha; o1.z *= alpha; o1.w *= alpha;
        o2.x *= alpha; o2.y *= alpha; o2.z *= alpha; o2.w *= alpha;
        o3.x *= alpha; o3.y *= alpha; o3.z *= alpha; o3.w *= alpha;

        Ps[r][c0 + 0] = p0; Ps[r][c0 + 1] = p1;
        Ps[r][c0 + 2] = p2; Ps[r][c0 + 3] = p3;
        __syncthreads();

        // O += P . V  (thread's d-range: g*16 .. g*16+15)
        const int dbase = g * 16;
        #pragma unroll 8
        for (int c = 0; c < 32; ++c) {
            float p = Ps[r][c];
            const float* vp = &Vs[c][dbase];
            float4 va = *(const float4*)(vp + 0);
            float4 vb = *(const float4*)(vp + 4);
            float4 vc = *(const float4*)(vp + 8);
            float4 vd = *(const float4*)(vp + 12);
            o0.x += p*va.x; o0.y += p*va.y; o0.z += p*va.z; o0.w += p*va.w;
            o1.x += p*vb.x; o1.y += p*vb.y; o1.z += p*vb.z; o1.w += p*vb.w;
            o2.x += p*vc.x; o2.y += p*vc.y; o2.z += p*vc.z; o2.w += p*vc.w;
            o3.x += p*vd.x; o3.y += p*vd.y; o3.z += p*vd.z; o3.w += p*vd.w;
        }
    }

    const int q = q0 + r;
    if (q < N_) {
        float inv = 1.f / l_sum;
        o0.x *= inv; o0.y *= inv; o0.z *= inv; o0.w *= inv;
        o1.x *= inv; o1.y *= inv; o1.z *= inv; o1.w *= inv;
        o2.x *= inv; o2.y *= inv; o2.z *= inv; o2.w *= inv;
        o3.x *= inv; o3.y *= inv; o3.z *= inv; o3.w *= inv;
        float* op = attn_out + ((size_t)(b * N_ + q)) * C_ + h * D_ + g * 16;
        *(float4*)(op + 0)  = o0;
        *(float4*)(op + 4)  = o1;
        *(float4*)(op + 8)  = o2;
        *(float4*)(op + 12) = o3;
    }
}

// ---------------------------------------------------------------------------
extern "C" void kernel_launch(void* const* d_in, const int* in_sizes, int n_in,
                              void* d_out, int out_size, void* d_ws, size_t ws_size,
                              hipStream_t stream)
{
    const float* x        = (const float*)d_in[0];
    const float* qkv_w    = (const float*)d_in[1];
    const float* qkv_b    = (const float*)d_in[2];
    const float* q_norm_w = (const float*)d_in[3];
    const float* k_norm_w = (const float*)d_in[4];
    const float* proj_w   = (const float*)d_in[5];
    const float* proj_b   = (const float*)d_in[6];
    float* out = (float*)d_out;

    float* qkv      = (float*)d_ws;                    // M_ x 9600
    float* attn_out = qkv + (size_t)M_ * C3_;          // M_ x 3200

    dim3 blk(256);

    // 1) QKV GEMM: [8200,3200] @ [3200,9600] + bias
    dim3 g1(C3_ / 64, (M_ + 63) / 64);
    gemm_bias_f32<<<g1, blk, 0, stream>>>(x, qkv_w, qkv_b, qkv, M_, C3_, C_);

    // 2) RMSNorm on q and k slices
    rmsnorm_kernel<<<dim3(M_ * 2), blk, 0, stream>>>(qkv, q_norm_w, k_norm_w);

    // 3) Flash attention
    dim3 gf((N_ + 31) / 32, H_, B_);
    flash_kernel<<<gf, blk, 0, stream>>>(qkv, attn_out);

    // 4) Output projection: [8200,3200] @ [3200,3200] + bias
    dim3 g2(C_ / 64, (M_ + 63) / 64);
    gemm_bias_f32<<<g2, blk, 0, stream>>>(attn_out, proj_w, proj_b, out, M_, C_, C_);
}